// Round 7
// baseline (157.115 us; speedup 1.0000x reference)
//
#include <hip/hip_runtime.h>
#include <cstdint>
#include <cstddef>

typedef __attribute__((ext_vector_type(8))) __bf16 bf16x8;
typedef __attribute__((ext_vector_type(16))) float f32x16;
typedef __attribute__((ext_vector_type(8))) unsigned short u16x8;

__device__ __forceinline__ unsigned short f2bf(float f) {
  union { float f; unsigned u; } v; v.f = f;
  unsigned u = v.u;
  return (unsigned short)((u + 0x7FFFu + ((u >> 16) & 1u)) >> 16);
}

__device__ __forceinline__ void async16(const void* g, void* l) {
  __builtin_amdgcn_global_load_lds(
      (const __attribute__((address_space(1))) unsigned int*)g,
      (__attribute__((address_space(3))) unsigned int*)l, 16, 0, 0);
}

// ---------------- fused prologue: x fp32->bf16 (blocks 0..8191) +
//                  W expand -> M stored [N][K] bf16 (blocks 8192..9215) ----------------
__global__ __launch_bounds__(256) void prep_kern(const float* __restrict__ x,
                                                 const float* __restrict__ W,
                                                 unsigned short* __restrict__ xb,
                                                 unsigned short* __restrict__ Mb) {
  int b = blockIdx.x;
  if (b < 8192) {
    int idx = b * 256 + threadIdx.x;
    const float4* src = (const float4*)x + (size_t)idx * 2;
    float4 a = src[0], b4 = src[1];
    u16x8 v;
    v[0] = f2bf(a.x); v[1] = f2bf(a.y); v[2] = f2bf(a.z); v[3] = f2bf(a.w);
    v[4] = f2bf(b4.x); v[5] = f2bf(b4.y); v[6] = f2bf(b4.z); v[7] = f2bf(b4.w);
    *((u16x8*)xb + idx) = v;
  } else {
    int pair = (b - 8192) * 4 + (threadIdx.x >> 6);  // (i,j) flat index
    int sub = threadIdx.x >> 6, c = threadIdx.x & 63;
    int i = pair >> 6, j = pair & 63;
    __shared__ unsigned short w16[4][64];
    w16[sub][c] = f2bf(W[(size_t)pair * 64 + c]);
    __syncthreads();
    unsigned short* dst = Mb + (size_t)(i * 64 + c) * 4096 + j * 64;
#pragma unroll
    for (int g = 0; g < 8; ++g) {
      u16x8 v;
#pragma unroll
      for (int e = 0; e < 8; ++e) v[e] = w16[sub][(c - (g * 8 + e)) & 63];
      *(u16x8*)(dst + g * 8) = v;
    }
  }
}

// ---------------- main GEMM: 256x256, BK=64, 4-phase schedule, 32x32x16 MFMA ----------------
// Round-5 schedule (deep prefetch, 7 barriers/tile, tile-local fragments), 32x32x16
// fragments (4x2 sub-tiles of 32x32 per wave), and a beat-proof LDS involution:
//   g(row) = (row&7) ^ (((row>>3)&3)<<1);   LDS(row,slot) holds chunk slot^g(row)
// Slot varies across lanes under both consecutive-8 and strided-8 beat groupings ->
// conflict-free ds_read_b128 regardless of HW beat structure.
#define FE asm volatile("" ::: "memory")
#define BARRIER() do { FE; __builtin_amdgcn_s_barrier(); FE; } while (0)

#define MFQ32(AF, MB, NI, BF)                                                    \
  __builtin_amdgcn_s_setprio(1);                                                 \
  _Pragma("unroll") for (int ks = 0; ks < 4; ++ks)                               \
      _Pragma("unroll") for (int mi = 0; mi < 2; ++mi)                           \
      acc[(MB) + mi][NI] = __builtin_amdgcn_mfma_f32_32x32x16_bf16(              \
          AF[mi][ks], BF[ks], acc[(MB) + mi][NI], 0, 0, 0);                      \
  __builtin_amdgcn_s_setprio(0);

// MODE: 0 steady, 1 = tt==62 (no stages, boundary vmcnt(0)), 2 = tt==63 (final)
#define TILE_BODY(TT, CUR, MODE)                                                 \
  do {                                                                           \
    const char* pa = lds + (CUR) * 65536 + wm * 128;                             \
    const char* pb = lds + (CUR) * 65536 + 32768 + wn * 128;                     \
    bf16x8 a0[2][4], a1[2][4], bl[4], bh[4];                                     \
    /* ---- P0: read aL(8)+bL(4); MFMA (mLow, n0) ---- */                        \
    _Pragma("unroll") for (int mi = 0; mi < 2; ++mi)                             \
        _Pragma("unroll") for (int ks = 0; ks < 4; ++ks)                         \
        a0[mi][ks] = *(const bf16x8*)(pa + mi * 4096 + koff[ks]);                \
    _Pragma("unroll") for (int ks = 0; ks < 4; ++ks)                             \
        bl[ks] = *(const bf16x8*)(pb + koff[ks]);                                \
    BARRIER();                                                                   \
    MFQ32(a0, 0, 0, bl)                                                          \
    BARRIER();                                                                   \
    /* ---- P1: read bH(4); MFMA (mLow, n1) ---- */                              \
    _Pragma("unroll") for (int ks = 0; ks < 4; ++ks)                             \
        bh[ks] = *(const bf16x8*)(pb + 4096 + koff[ks]);                         \
    BARRIER();                                                                   \
    MFQ32(a0, 0, 1, bh)                                                          \
    BARRIER();                                                                   \
    /* ---- P2: read aH(8); stage t+2 B; MFMA (mHigh, n1) ---- */                \
    _Pragma("unroll") for (int mi = 0; mi < 2; ++mi)                             \
        _Pragma("unroll") for (int ks = 0; ks < 4; ++ks)                         \
        a1[mi][ks] = *(const bf16x8*)(pa + (2 + mi) * 4096 + koff[ks]);          \
    if ((MODE) == 0) {                                                           \
      stage((TT) + 2, 2);                                                        \
      stage((TT) + 2, 3);                                                        \
    }                                                                            \
    BARRIER();                                                                   \
    MFQ32(a1, 2, 1, bh)                                                          \
    BARRIER();                                                                   \
    /* ---- P3: stage t+2 A; reg-only MFMA (mHigh, n0); vmcnt + 1 barrier ---- */\
    if ((MODE) == 0) {                                                           \
      stage((TT) + 2, 0);                                                        \
      stage((TT) + 2, 1);                                                        \
    }                                                                            \
    MFQ32(a1, 2, 0, bl)                                                          \
    if ((MODE) == 0)                                                             \
      asm volatile("s_waitcnt vmcnt(8)" ::: "memory");                           \
    else if ((MODE) == 1)                                                        \
      asm volatile("s_waitcnt vmcnt(0)" ::: "memory");                           \
    if ((MODE) < 2) BARRIER();                                                   \
  } while (0)

__global__ __launch_bounds__(512, 2) void gemm8(const unsigned short* __restrict__ A,
                                                const unsigned short* __restrict__ B,
                                                float* __restrict__ C) {
  __shared__ __align__(16) char lds[131072];
  int bid = blockIdx.x;
  int swz = (bid & 7) * 32 + (bid >> 3);  // bijective: 256 = 8*32
  int bm = swz >> 4, bn = swz & 15;
  int t = threadIdx.x;
  int w = t >> 6, l = t & 63;
  int wm = (w >> 2) * 128;  // 2 M-groups
  int wn = (w & 3) * 64;    // 4 N-groups

  f32x16 acc[4][2];
#pragma unroll
  for (int a_ = 0; a_ < 4; ++a_)
#pragma unroll
    for (int b_ = 0; b_ < 2; ++b_) acc[a_][b_] = (f32x16)(0.f);

  const int rowin = w * 8 + (l >> 3);  // staging row within 64-row group
  // store: chunk = slot ^ g(row); slot = l&7, row&7 = l>>3, (row>>3)&3 = w&3
  const int cslot = (l & 7) ^ (l >> 3) ^ ((w & 3) << 1);
  // read: row = l&31, chunk = ks*2 + (l>>5); slot = chunk ^ g(row),
  // g(row) = (row&7) ^ (((row>>3)&3)<<1) = (l&7) ^ (((l>>3)&3)<<1)
  int koff[4];
#pragma unroll
  for (int ks = 0; ks < 4; ++ks)
    koff[ks] = (l & 31) * 128 +
               (((ks * 2 + (l >> 5)) ^ (l & 7) ^ (((l >> 3) & 3) << 1)) * 16);

  const size_t abase = (size_t)bm * 256 * 4096;
  const size_t bbase = (size_t)bn * 256 * 4096;

  auto stage = [&](int kt, int c) {
    const unsigned short* mat = (c < 2) ? A : B;
    size_t gbase = (c < 2) ? abase : bbase;
    int half = c & 1;
    char* ldst = lds + (kt & 1) * 65536 + ((c < 2) ? 0 : 32768) + half * 16384 + w * 1024;
#pragma unroll
    for (int i = 0; i < 2; ++i) {
      int r = half * 128 + i * 64 + rowin;
      async16(mat + gbase + (size_t)r * 4096 + kt * 64 + cslot * 8, ldst + i * 8192);
    }
  };

  // prologue: tiles 0 and 1 fully staged (8 + 8 loads); tile 0 landed
#pragma unroll
  for (int c = 0; c < 4; ++c) stage(0, c);
#pragma unroll
  for (int c = 0; c < 4; ++c) stage(1, c);
  asm volatile("s_waitcnt vmcnt(8)" ::: "memory");
  BARRIER();

  for (int tt = 0; tt < 62; tt += 2) {
    TILE_BODY(tt, 0, 0);
    TILE_BODY(tt + 1, 1, 0);
  }
  TILE_BODY(62, 0, 1);
  TILE_BODY(63, 1, 2);

#undef TILE_BODY
#undef MFQ32

  // 32x32 C/D layout (m74/m101-verified): col = lane&31,
  // row = (reg&3) + 8*(reg>>2) + 4*(lane>>5)
  int rlo = 4 * (l >> 5);
#pragma unroll
  for (int mi = 0; mi < 4; ++mi) {
#pragma unroll
    for (int ni = 0; ni < 2; ++ni) {
      int col = bn * 256 + wn + ni * 32 + (l & 31);
#pragma unroll
      for (int rg = 0; rg < 16; ++rg) {
        int row = bm * 256 + wm + mi * 32 + (rg & 3) + 8 * (rg >> 2) + rlo;
        C[(size_t)row * 4096 + col] = acc[mi][ni][rg];
      }
    }
  }
}

// ---------------- fallback (no workspace): fp32 register-blocked ----------------
__global__ __launch_bounds__(256) void fallback_kern(const float* __restrict__ x,
                                                     const float* __restrict__ W,
                                                     float* __restrict__ out) {
  int bi = blockIdx.x & 63;
  int bb = blockIdx.x >> 6;
  int t = threadIdx.x;
  int m = t & 63;
  int cg = t >> 6;
  __shared__ float xs[64][65];
  __shared__ float ws[64];
  float acc[16];
#pragma unroll
  for (int e = 0; e < 16; ++e) acc[e] = 0.f;
  for (int j = 0; j < 64; ++j) {
    __syncthreads();
#pragma unroll
    for (int r = 0; r < 16; ++r) {
      int idx = t + 256 * r;
      int rr = idx >> 6, cc = idx & 63;
      xs[rr][cc] = x[(size_t)(bb * 64 + rr) * 4096 + j * 64 + cc];
    }
    if (t < 64) ws[t] = W[((size_t)(bi * 64 + j)) * 64 + t];
    __syncthreads();
    float xr[64];
#pragma unroll
    for (int e = 0; e < 64; ++e) xr[e] = xs[m][(cg * 16 + e) & 63];
#pragma unroll
    for (int mm = 0; mm < 64; ++mm) {
      float wv = ws[mm];
#pragma unroll
      for (int cc2 = 0; cc2 < 16; ++cc2)
        acc[cc2] = __builtin_fmaf(xr[(cc2 - mm) & 63], wv, acc[cc2]);
    }
  }
  float* dst = out + (size_t)(bb * 64 + m) * 4096 + bi * 64 + cg * 16;
#pragma unroll
  for (int cc2 = 0; cc2 < 16; ++cc2) dst[cc2] = acc[cc2];
}

extern "C" void kernel_launch(void* const* d_in, const int* in_sizes, int n_in,
                              void* d_out, int out_size, void* d_ws, size_t ws_size,
                              hipStream_t stream) {
  const float* x = (const float*)d_in[0];
  const float* W = (const float*)d_in[1];
  float* out = (float*)d_out;
  const size_t need = (size_t)2 * 4096 * 4096 * sizeof(unsigned short);  // 64 MB
  if (ws_size >= need) {
    unsigned short* xb = (unsigned short*)d_ws;
    unsigned short* Mb = xb + (size_t)4096 * 4096;
    prep_kern<<<dim3(9216), dim3(256), 0, stream>>>(x, W, xb, Mb);
    gemm8<<<dim3(256), dim3(512), 0, stream>>>(xb, Mb, out);
  } else {
    fallback_kern<<<dim3(4096), dim3(256), 0, stream>>>(x, W, out);
  }
}

// Round 8
// 137.905 us; speedup vs baseline: 1.1393x; 1.1393x over previous
//
#include <hip/hip_runtime.h>
#include <cstdint>
#include <cstddef>

typedef __attribute__((ext_vector_type(8))) __bf16 bf16x8;
typedef __attribute__((ext_vector_type(4))) float f32x4;
typedef __attribute__((ext_vector_type(8))) unsigned short u16x8;

__device__ __forceinline__ unsigned short f2bf(float f) {
  union { float f; unsigned u; } v; v.f = f;
  unsigned u = v.u;
  return (unsigned short)((u + 0x7FFFu + ((u >> 16) & 1u)) >> 16);
}

__device__ __forceinline__ void async16(const void* g, void* l) {
  __builtin_amdgcn_global_load_lds(
      (const __attribute__((address_space(1))) unsigned int*)g,
      (__attribute__((address_space(3))) unsigned int*)l, 16, 0, 0);
}

// ---------------- fused prologue: x fp32->bf16 (blocks 0..8191) +
//                  W expand -> M stored [N][K] bf16 (blocks 8192..9215) ----------------
__global__ __launch_bounds__(256) void prep_kern(const float* __restrict__ x,
                                                 const float* __restrict__ W,
                                                 unsigned short* __restrict__ xb,
                                                 unsigned short* __restrict__ Mb) {
  int b = blockIdx.x;
  if (b < 8192) {
    int idx = b * 256 + threadIdx.x;
    const float4* src = (const float4*)x + (size_t)idx * 2;
    float4 a = src[0], b4 = src[1];
    u16x8 v;
    v[0] = f2bf(a.x); v[1] = f2bf(a.y); v[2] = f2bf(a.z); v[3] = f2bf(a.w);
    v[4] = f2bf(b4.x); v[5] = f2bf(b4.y); v[6] = f2bf(b4.z); v[7] = f2bf(b4.w);
    *((u16x8*)xb + idx) = v;
  } else {
    int pair = (b - 8192) * 4 + (threadIdx.x >> 6);  // (i,j) flat index
    int sub = threadIdx.x >> 6, c = threadIdx.x & 63;
    int i = pair >> 6, j = pair & 63;
    __shared__ unsigned short w16[4][64];
    w16[sub][c] = f2bf(W[(size_t)pair * 64 + c]);
    __syncthreads();
    unsigned short* dst = Mb + (size_t)(i * 64 + c) * 4096 + j * 64;
#pragma unroll
    for (int g = 0; g < 8; ++g) {
      u16x8 v;
#pragma unroll
      for (int e = 0; e < 8; ++e) v[e] = w16[sub][(c - (g * 8 + e)) & 63];
      *(u16x8*)(dst + g * 8) = v;
    }
  }
}

// ---------------- main GEMM: 256x256, BK=64, 16x16x32, 3-barrier tile ----------------
// Round-5 data path (16x16x32 fragments, slot^(row&7) involution, 0 conflicts,
// deep t+2 prefetch with vmcnt(8)) with barriers cut 7 -> 3 per K-tile:
//   S0: read aL(8)+bL(4)+bH(4); MFMA (0,0),(0,1)    [reads retired via MFMA lgkm]
//   b1; S1: read aH(8); stage t+2 B; MFMA (1,1)
//   b2; stage t+2 A; MFMA (1,0); vmcnt(8); b3 (boundary)
// b1 guards stage-B WAR, b2 guards stage-A WAR, b3 guards buffer swap RAW.
#define FE asm volatile("" ::: "memory")
#define BARRIER() do { FE; __builtin_amdgcn_s_barrier(); FE; } while (0)

#define MFQ(AF, MB, BF, NB)                                                      \
  __builtin_amdgcn_s_setprio(1);                                                 \
  _Pragma("unroll") for (int ks = 0; ks < 2; ++ks)                               \
      _Pragma("unroll") for (int mi = 0; mi < 4; ++mi)                           \
      _Pragma("unroll") for (int ni = 0; ni < 2; ++ni)                           \
      acc[(MB) + mi][(NB) + ni] = __builtin_amdgcn_mfma_f32_16x16x32_bf16(       \
          AF[mi][ks], BF[ni][ks], acc[(MB) + mi][(NB) + ni], 0, 0, 0);           \
  __builtin_amdgcn_s_setprio(0);

// MODE: 0 steady, 1 = tt==62 (no stages, boundary vmcnt(0)), 2 = tt==63 (final)
#define TILE_BODY(TT, CUR, MODE)                                                 \
  do {                                                                           \
    const char* pa = lds + (CUR) * 65536 + wm * 128;                             \
    const char* pb = lds + (CUR) * 65536 + 32768 + wn * 128;                     \
    bf16x8 a0[4][2], a1[4][2], bl[2][2], bh[2][2];                               \
    /* ---- S0: read aL+bL+bH; MFMA (0,0) and (0,1) ---- */                      \
    _Pragma("unroll") for (int mi = 0; mi < 4; ++mi)                             \
        _Pragma("unroll") for (int ks = 0; ks < 2; ++ks)                         \
        a0[mi][ks] = *(const bf16x8*)(pa + koff[ks] + mi * 2048);                \
    _Pragma("unroll") for (int ni = 0; ni < 2; ++ni)                             \
        _Pragma("unroll") for (int ks = 0; ks < 2; ++ks)                         \
        bl[ni][ks] = *(const bf16x8*)(pb + koff[ks] + ni * 2048);                \
    _Pragma("unroll") for (int ni = 0; ni < 2; ++ni)                             \
        _Pragma("unroll") for (int ks = 0; ks < 2; ++ks)                         \
        bh[ni][ks] = *(const bf16x8*)(pb + koff[ks] + (2 + ni) * 2048);          \
    MFQ(a0, 0, bl, 0)                                                            \
    MFQ(a0, 0, bh, 2)                                                            \
    BARRIER(); /* b1: all waves consumed aL,bL,bH -> B region reusable */        \
    /* ---- S1: read aH; stage t+2 B; MFMA (1,1) ---- */                         \
    _Pragma("unroll") for (int mi = 0; mi < 4; ++mi)                             \
        _Pragma("unroll") for (int ks = 0; ks < 2; ++ks)                         \
        a1[mi][ks] = *(const bf16x8*)(pa + koff[ks] + (4 + mi) * 2048);          \
    if ((MODE) == 0) {                                                           \
      stage((TT) + 2, 2);                                                        \
      stage((TT) + 2, 3);                                                        \
    }                                                                            \
    MFQ(a1, 4, bh, 2)                                                            \
    BARRIER(); /* b2: all waves consumed aH -> A region reusable */              \
    /* ---- S2: stage t+2 A; MFMA (1,0); boundary vmcnt + barrier ---- */        \
    if ((MODE) == 0) {                                                           \
      stage((TT) + 2, 0);                                                        \
      stage((TT) + 2, 1);                                                        \
    }                                                                            \
    MFQ(a1, 4, bl, 0)                                                            \
    if ((MODE) == 0)                                                             \
      asm volatile("s_waitcnt vmcnt(8)" ::: "memory");                           \
    else if ((MODE) == 1)                                                        \
      asm volatile("s_waitcnt vmcnt(0)" ::: "memory");                           \
    if ((MODE) < 2) BARRIER(); /* b3: buffer swap */                             \
  } while (0)

__global__ __launch_bounds__(512, 2) void gemm8(const unsigned short* __restrict__ A,
                                                const unsigned short* __restrict__ B,
                                                float* __restrict__ C) {
  __shared__ __align__(16) char lds[131072];
  int bid = blockIdx.x;
  int swz = (bid & 7) * 32 + (bid >> 3);  // bijective: 256 = 8*32
  int bm = swz >> 4, bn = swz & 15;
  int t = threadIdx.x;
  int w = t >> 6, l = t & 63;
  int wm = (w >> 2) * 128;  // 2 M-groups
  int wn = (w & 3) * 64;    // 4 N-groups

  f32x4 acc[8][4];
#pragma unroll
  for (int a_ = 0; a_ < 8; ++a_)
#pragma unroll
    for (int b_ = 0; b_ < 4; ++b_) acc[a_][b_] = (f32x4){0.f, 0.f, 0.f, 0.f};

  const int rowin = w * 8 + (l >> 3);    // staging row within 64-row group
  const int cslot = (l & 7) ^ (l >> 3);  // pre-swizzled global k-slot
  int koff[2];
#pragma unroll
  for (int ks = 0; ks < 2; ++ks)
    koff[ks] = (l & 15) * 128 + ((ks * 4 + (l >> 4)) ^ (l & 7)) * 16;

  const size_t abase = (size_t)bm * 256 * 4096;
  const size_t bbase = (size_t)bn * 256 * 4096;

  auto stage = [&](int kt, int c) {
    const unsigned short* mat = (c < 2) ? A : B;
    size_t gbase = (c < 2) ? abase : bbase;
    int half = c & 1;
    char* ldst = lds + (kt & 1) * 65536 + ((c < 2) ? 0 : 32768) + half * 16384 + w * 1024;
#pragma unroll
    for (int i = 0; i < 2; ++i) {
      int r = half * 128 + i * 64 + rowin;
      async16(mat + gbase + (size_t)r * 4096 + kt * 64 + cslot * 8, ldst + i * 8192);
    }
  };

  // prologue: tiles 0 and 1 fully staged (8 + 8 loads); tile 0 landed
#pragma unroll
  for (int c = 0; c < 4; ++c) stage(0, c);
#pragma unroll
  for (int c = 0; c < 4; ++c) stage(1, c);
  asm volatile("s_waitcnt vmcnt(8)" ::: "memory");
  BARRIER();

  for (int tt = 0; tt < 62; tt += 2) {
    TILE_BODY(tt, 0, 0);
    TILE_BODY(tt + 1, 1, 0);
  }
  TILE_BODY(62, 0, 1);
  TILE_BODY(63, 1, 2);

#undef TILE_BODY
#undef MFQ

  // C/D layout (m89-verified): col = lane&15, row = (lane>>4)*4 + reg
  int r0 = (l >> 4) * 4;
#pragma unroll
  for (int mi = 0; mi < 8; ++mi) {
    size_t row = (size_t)(bm * 256 + wm + mi * 16 + r0);
#pragma unroll
    for (int ni = 0; ni < 4; ++ni) {
      int col = bn * 256 + wn + ni * 16 + (l & 15);
#pragma unroll
      for (int r = 0; r < 4; ++r)
        C[(row + r) * 4096 + col] = acc[mi][ni][r];
    }
  }
}

// ---------------- fallback (no workspace): fp32 register-blocked ----------------
__global__ __launch_bounds__(256) void fallback_kern(const float* __restrict__ x,
                                                     const float* __restrict__ W,
                                                     float* __restrict__ out) {
  int bi = blockIdx.x & 63;
  int bb = blockIdx.x >> 6;
  int t = threadIdx.x;
  int m = t & 63;
  int cg = t >> 6;
  __shared__ float xs[64][65];
  __shared__ float ws[64];
  float acc[16];
#pragma unroll
  for (int e = 0; e < 16; ++e) acc[e] = 0.f;
  for (int j = 0; j < 64; ++j) {
    __syncthreads();
#pragma unroll
    for (int r = 0; r < 16; ++r) {
      int idx = t + 256 * r;
      int rr = idx >> 6, cc = idx & 63;
      xs[rr][cc] = x[(size_t)(bb * 64 + rr) * 4096 + j * 64 + cc];
    }
    if (t < 64) ws[t] = W[((size_t)(bi * 64 + j)) * 64 + t];
    __syncthreads();
    float xr[64];
#pragma unroll
    for (int e = 0; e < 64; ++e) xr[e] = xs[m][(cg * 16 + e) & 63];
#pragma unroll
    for (int mm = 0; mm < 64; ++mm) {
      float wv = ws[mm];
#pragma unroll
      for (int cc2 = 0; cc2 < 16; ++cc2)
        acc[cc2] = __builtin_fmaf(xr[(cc2 - mm) & 63], wv, acc[cc2]);
    }
  }
  float* dst = out + (size_t)(bb * 64 + m) * 4096 + bi * 64 + cg * 16;
#pragma unroll
  for (int cc2 = 0; cc2 < 16; ++cc2) dst[cc2] = acc[cc2];
}

extern "C" void kernel_launch(void* const* d_in, const int* in_sizes, int n_in,
                              void* d_out, int out_size, void* d_ws, size_t ws_size,
                              hipStream_t stream) {
  const float* x = (const float*)d_in[0];
  const float* W = (const float*)d_in[1];
  float* out = (float*)d_out;
  const size_t need = (size_t)2 * 4096 * 4096 * sizeof(unsigned short);  // 64 MB
  if (ws_size >= need) {
    unsigned short* xb = (unsigned short*)d_ws;
    unsigned short* Mb = xb + (size_t)4096 * 4096;
    prep_kern<<<dim3(9216), dim3(256), 0, stream>>>(x, W, xb, Mb);
    gemm8<<<dim3(256), dim3(512), 0, stream>>>(xb, Mb, out);
  } else {
    fallback_kern<<<dim3(4096), dim3(256), 0, stream>>>(x, W, out);
  }
}